// Round 5
// baseline (788.342 us; speedup 1.0000x reference)
//
#include <hip/hip_runtime.h>
#include <math.h>

#define B_   8
#define Hs   56
#define Ws   56
#define Cc   768
#define NHh  12
#define HDd  64
#define Nt   3137
#define HW_  3136
#define C3   2304
#define SCALE 0.125f
#define Mrows (B_ * Nt)        // 25096
#define Mpad  (197 * 128)      // 25216

typedef _Float16 half8  __attribute__((ext_vector_type(8)));
typedef _Float16 half4  __attribute__((ext_vector_type(4)));
typedef _Float16 half2_ __attribute__((ext_vector_type(2)));
typedef float floatx4 __attribute__((ext_vector_type(4)));

__device__ inline float fdot2f(half2_ a, half2_ b, float c) {
#if __has_builtin(__builtin_amdgcn_fdot2)
    return __builtin_amdgcn_fdot2(a, b, c, false);
#else
    return fmaf((float)a.x, (float)b.x, fmaf((float)a.y, (float)b.y, c));
#endif
}

// ---------------- scratch (__device__ globals) -----------------------------
__device__ _Float16 g_qkvh[(size_t)Mrows * C3];
__device__ float    g_Ocol[(size_t)B_ * NHh * HW_ * HDd];
__device__ float    g_mcol[(size_t)B_ * NHh * HW_];
__device__ float    g_lcol[(size_t)B_ * NHh * HW_];
__device__ _Float16 g_xh[(size_t)Mpad * Cc];
__device__ _Float16 g_attH[(size_t)Mpad * Cc];
__device__ _Float16 g_WqkvT[(size_t)C3 * Cc];
__device__ _Float16 g_WprojT[(size_t)Cc * Cc];
__device__ float    g_clsP[(size_t)B_ * NHh * 4 * 66];

// ---------------- fp32 -> fp16 convert -------------------------------------
__global__ __launch_bounds__(256) void cvt_f16(
    const float* __restrict__ in, _Float16* __restrict__ out, int n4)
{
    for (int i = blockIdx.x * 256 + threadIdx.x; i < n4; i += gridDim.x * 256) {
        float4 v = ((const float4*)in)[i];
        half4 h = { (_Float16)v.x, (_Float16)v.y, (_Float16)v.z, (_Float16)v.w };
        ((half4*)out)[i] = h;
    }
}

// ---------------- fp32 [R][Cq] -> fp16 transposed [Cq][R] ------------------
__global__ __launch_bounds__(256) void transpose_f16(
    const float* __restrict__ in, _Float16* __restrict__ out, int R, int Cq)
{
    __shared__ float t[32][33];
    const int c0 = blockIdx.x * 32, r0 = blockIdx.y * 32;
    const int tx = threadIdx.x & 31, ty = threadIdx.x >> 5;
#pragma unroll
    for (int i = 0; i < 32; i += 8)
        t[ty + i][tx] = in[(size_t)(r0 + ty + i) * Cq + c0 + tx];
    __syncthreads();
#pragma unroll
    for (int i = 0; i < 32; i += 8)
        out[(size_t)(c0 + ty + i) * R + r0 + tx] = (_Float16)t[tx][ty + i];
}

// ---------------------------------------------------------------------------
// fp16 MFMA GEMM: C[M,Nd] = A[Mpad,K] @ Bt[Nd,K]^T (+bias).
// 128x128 tile, BK=32, swizzled conflict-free staging. Epilogue routes the
// accumulator through LDS (4 passes of 32 rows x 128 cols) so global stores
// are 128B-contiguous per row -> no partial-line write amplification.
// ---------------------------------------------------------------------------
template <typename OutT>
__global__ __launch_bounds__(256) void gemm_f16(
    const _Float16* __restrict__ A, const _Float16* __restrict__ Bt,
    const float* __restrict__ bias, OutT* __restrict__ Cm,
    int M, int Nd, int K)
{
    __shared__ __align__(16) union {
        struct { _Float16 Ah[128 * 32]; _Float16 Bh[128 * 32]; } st;
        float Ep[32][133];
    } sm;

    const int tid = threadIdx.x;
    const int wave = tid >> 6, lane = tid & 63;
    const int wm = wave & 1, wn = wave >> 1;

    // panel swizzle: 16 row-blocks per panel, col-major within panel
    const int bid = blockIdx.y * gridDim.x + blockIdx.x;
    const int perPanel = gridDim.x * 16;
    const int panel = bid / perPanel;
    const int rowsIn = min(16, (int)gridDim.y - panel * 16);
    const int rem = bid - panel * perPanel;
    const int by = panel * 16 + rem % rowsIn;
    const int bx = rem / rowsIn;
    const int mBase = by * 128, nBase = bx * 128;

    const int u0 = wave * 128 + lane, u1 = u0 + 64;
    const int m0 = ((u0 >> 6) << 4) + (u0 & 15), kc0 = (u0 >> 4) & 3;
    const int m1 = ((u1 >> 6) << 4) + (u1 & 15), kc1 = (u1 >> 4) & 3;
    const _Float16* ga0 = A + (size_t)(mBase + m0) * K + kc0 * 8;
    const _Float16* ga1 = A + (size_t)(mBase + m1) * K + kc1 * 8;
    const _Float16* gb0 = Bt + (size_t)(nBase + m0) * K + kc0 * 8;
    const _Float16* gb1 = Bt + (size_t)(nBase + m1) * K + kc1 * 8;
    _Float16* la0 = &sm.st.Ah[(u0 >> 6) * 512];
    _Float16* la1 = &sm.st.Ah[(u1 >> 6) * 512];
    _Float16* lb0 = &sm.st.Bh[(u0 >> 6) * 512];
    _Float16* lb1 = &sm.st.Bh[(u1 >> 6) * 512];

    const int aoff = wm * 2048 + (lane >> 4) * 128 + (lane & 15) * 8;
    const int boff = wn * 2048 + (lane >> 4) * 128 + (lane & 15) * 8;

    floatx4 acc[4][4] = {};

    for (int k0 = 0; k0 < K; k0 += 32) {
        __syncthreads();
        __builtin_amdgcn_global_load_lds((const __attribute__((address_space(1))) void*)ga0,
                                         (__attribute__((address_space(3))) void*)la0, 16, 0, 0);
        __builtin_amdgcn_global_load_lds((const __attribute__((address_space(1))) void*)ga1,
                                         (__attribute__((address_space(3))) void*)la1, 16, 0, 0);
        __builtin_amdgcn_global_load_lds((const __attribute__((address_space(1))) void*)gb0,
                                         (__attribute__((address_space(3))) void*)lb0, 16, 0, 0);
        __builtin_amdgcn_global_load_lds((const __attribute__((address_space(1))) void*)gb1,
                                         (__attribute__((address_space(3))) void*)lb1, 16, 0, 0);
        ga0 += 32; ga1 += 32; gb0 += 32; gb1 += 32;
        __syncthreads();

        half8 a[4], b[4];
#pragma unroll
        for (int mi = 0; mi < 4; ++mi) a[mi] = *(const half8*)&sm.st.Ah[aoff + mi * 512];
#pragma unroll
        for (int ni = 0; ni < 4; ++ni) b[ni] = *(const half8*)&sm.st.Bh[boff + ni * 512];
#pragma unroll
        for (int mi = 0; mi < 4; ++mi)
#pragma unroll
            for (int ni = 0; ni < 4; ++ni)
                acc[mi][ni] = __builtin_amdgcn_mfma_f32_16x16x32_f16(
                    b[ni], a[mi], acc[mi][ni], 0, 0, 0);
    }

    // ---------------- epilogue via LDS (coalesced stores) ------------------
    const int r32 = tid >> 3;                 // 0..31
    const int cg  = (tid & 7) * 4;            // 0..28 (floats)
    const int mOut = mBase + (r32 >> 4) * 64 + (r32 & 15);  // + mi*16 per pass
    float4 bv[4];
#pragma unroll
    for (int k = 0; k < 4; ++k)
        bv[k] = bias ? *(const float4*)&bias[nBase + cg + 32 * k]
                     : make_float4(0.f, 0.f, 0.f, 0.f);

    const int wrow = wm * 16 + (lane & 15);
    const int wcol = wn * 64 + (lane >> 4) * 4;

    __syncthreads();
#pragma unroll
    for (int mi = 0; mi < 4; ++mi) {
#pragma unroll
        for (int ni = 0; ni < 4; ++ni) {
            floatx4 v = acc[mi][ni];
            float4 f = { v[0], v[1], v[2], v[3] };
            *(float4*)&sm.Ep[wrow][wcol + ni * 16] = f;
        }
        __syncthreads();
        const int m = mOut + mi * 16;
        if (m < M) {
            OutT* cp = &Cm[(size_t)m * Nd + nBase + cg];
#pragma unroll
            for (int k = 0; k < 4; ++k) {
                float4 v = *(float4*)&sm.Ep[r32][cg + 32 * k];
                if constexpr (sizeof(OutT) == 2) {
                    half4 h = { (_Float16)(v.x + bv[k].x), (_Float16)(v.y + bv[k].y),
                                (_Float16)(v.z + bv[k].z), (_Float16)(v.w + bv[k].w) };
                    *(half4*)(cp + 32 * k) = h;
                } else {
                    float4 o = make_float4(v.x + bv[k].x, v.y + bv[k].y,
                                           v.z + bv[k].z, v.w + bv[k].w);
                    *(float4*)(cp + 32 * k) = o;
                }
            }
        }
        __syncthreads();
    }
}

// ---------------------------------------------------------------------------
// Column attention partials: block (w,nh,b), 64 thr. All 57 scores in
// registers -> plain (non-online) softmax; K,V fp16 in LDS.
// ---------------------------------------------------------------------------
__global__ __launch_bounds__(64) void col_attn(
    const _Float16* __restrict__ qkvh, float* __restrict__ Ocol,
    float* __restrict__ mcol, float* __restrict__ lcol)
{
    const int w = blockIdx.x, nh = blockIdx.y, b = blockIdx.z;
    __shared__ __align__(16) _Float16 Kh[57 * HDd];
    __shared__ __align__(16) _Float16 Vh[57 * HDd];
    const int tid = threadIdx.x;

    for (int e = tid; e < 57 * 8; e += 64) {
        int j = e >> 3, c = e & 7;
        int n = (j == 0) ? 0 : ((j - 1) * Ws + w + 1);
        const _Float16* base = qkvh + (size_t)(b * Nt + n) * C3 + nh * HDd + c * 8;
        *(half8*)&Kh[j * HDd + c * 8] = *(const half8*)(base + Cc);
        *(half8*)&Vh[j * HDd + c * 8] = *(const half8*)(base + 2 * Cc);
    }
    __syncthreads();

    if (tid < Hs) {
        const int h = tid;
        const int n = h * Ws + w + 1;
        const _Float16* qp = qkvh + (size_t)(b * Nt + n) * C3 + nh * HDd;
        half8 q8[8];
#pragma unroll
        for (int c = 0; c < 8; ++c) q8[c] = ((const half8*)qp)[c];

        float s[57];
        for (int j = 0; j < 57; ++j) {
            const half8* kp = (const half8*)&Kh[j * HDd];
            float s0 = 0.f, s1 = 0.f, s2 = 0.f, s3 = 0.f;
#pragma unroll
            for (int c = 0; c < 8; ++c) {
                half8 kk = kp[c];
                const half2_* k2 = (const half2_*)&kk;
                const half2_* qq = (const half2_*)&q8[c];
                s0 = fdot2f(qq[0], k2[0], s0);
                s1 = fdot2f(qq[1], k2[1], s1);
                s2 = fdot2f(qq[2], k2[2], s2);
                s3 = fdot2f(qq[3], k2[3], s3);
            }
            s[j] = ((s0 + s1) + (s2 + s3)) * SCALE;
        }
        float m = s[0];
        for (int j = 1; j < 57; ++j) m = fmaxf(m, s[j]);
        float l = 0.f;
        for (int j = 0; j < 57; ++j) { s[j] = __expf(s[j] - m); l += s[j]; }

        float O[64] = {};
        for (int j = 0; j < 57; ++j) {
            const float p = s[j];
            const half8* vp = (const half8*)&Vh[j * HDd];
#pragma unroll
            for (int c = 0; c < 8; ++c) {
                half8 vv = vp[c];
#pragma unroll
                for (int q = 0; q < 8; ++q)
                    O[c * 8 + q] = fmaf(p, (float)vv[q], O[c * 8 + q]);
            }
        }
        const size_t qi = (size_t)((b * NHh + nh) * HW_ + h * Ws + w);
        mcol[qi] = m;
        lcol[qi] = l;
#pragma unroll
        for (int d4 = 0; d4 < 16; ++d4)
            *(float4*)&Ocol[qi * HDd + d4 * 4] = *(float4*)&O[d4 * 4];
    }
}

// ---------------------------------------------------------------------------
// Row attention + merge -> attH (fp16). Registers hold all 56 scores.
// ---------------------------------------------------------------------------
__global__ __launch_bounds__(64) void row_attn_merge(
    const _Float16* __restrict__ qkvh, const float* __restrict__ Ocol,
    const float* __restrict__ mcol, const float* __restrict__ lcol,
    _Float16* __restrict__ attH)
{
    const int h = blockIdx.x, nh = blockIdx.y, b = blockIdx.z;
    __shared__ __align__(16) _Float16 Kh[Ws * HDd];
    __shared__ __align__(16) _Float16 Vh[Ws * HDd];
    const int tid = threadIdx.x;

    for (int e = tid; e < Ws * 8; e += 64) {
        int j = e >> 3, c = e & 7;
        int n = h * Ws + j + 1;
        const _Float16* base = qkvh + (size_t)(b * Nt + n) * C3 + nh * HDd + c * 8;
        *(half8*)&Kh[j * HDd + c * 8] = *(const half8*)(base + Cc);
        *(half8*)&Vh[j * HDd + c * 8] = *(const half8*)(base + 2 * Cc);
    }
    __syncthreads();

    if (tid < Ws) {
        const int w = tid;
        const int n = h * Ws + w + 1;
        const _Float16* qp = qkvh + (size_t)(b * Nt + n) * C3 + nh * HDd;
        half8 q8[8];
#pragma unroll
        for (int c = 0; c < 8; ++c) q8[c] = ((const half8*)qp)[c];

        float s[56];
        for (int j = 0; j < 56; ++j) {
            const half8* kp = (const half8*)&Kh[j * HDd];
            float s0 = 0.f, s1 = 0.f, s2 = 0.f, s3 = 0.f;
#pragma unroll
            for (int c = 0; c < 8; ++c) {
                half8 kk = kp[c];
                const half2_* k2 = (const half2_*)&kk;
                const half2_* qq = (const half2_*)&q8[c];
                s0 = fdot2f(qq[0], k2[0], s0);
                s1 = fdot2f(qq[1], k2[1], s1);
                s2 = fdot2f(qq[2], k2[2], s2);
                s3 = fdot2f(qq[3], k2[3], s3);
            }
            s[j] = ((s0 + s1) + (s2 + s3)) * SCALE;
        }
        s[w] = -INFINITY;   // self masked
        float m = s[0];
        for (int j = 1; j < 56; ++j) m = fmaxf(m, s[j]);
        float l = 0.f;
        for (int j = 0; j < 56; ++j) { s[j] = __expf(s[j] - m); l += s[j]; }

        float O[64] = {};
        for (int j = 0; j < 56; ++j) {
            const float p = s[j];
            const half8* vp = (const half8*)&Vh[j * HDd];
#pragma unroll
            for (int c = 0; c < 8; ++c) {
                half8 vv = vp[c];
#pragma unroll
                for (int q = 0; q < 8; ++q)
                    O[c * 8 + q] = fmaf(p, (float)vv[q], O[c * 8 + q]);
            }
        }

        const size_t qi = (size_t)((b * NHh + nh) * HW_ + h * Ws + w);
        const float mc = mcol[qi], lc = lcol[qi];
        const float mn = fmaxf(mc, m);
        const float fc = __expf(mc - mn);
        const float fr = __expf(m - mn);
        const float inv = 1.f / (lc * fc + l * fr);
        _Float16* op = attH + (size_t)(b * Nt + n) * Cc + nh * HDd;
        const float* ocp = Ocol + qi * HDd;
#pragma unroll
        for (int d4 = 0; d4 < 16; ++d4) {
            float4 oc = *(const float4*)(ocp + d4 * 4);
            float* o4 = &O[d4 * 4];
            half4 r = { (_Float16)((oc.x * fc + o4[0] * fr) * inv),
                        (_Float16)((oc.y * fc + o4[1] * fr) * inv),
                        (_Float16)((oc.z * fc + o4[2] * fr) * inv),
                        (_Float16)((oc.w * fc + o4[3] * fr) * inv) };
            *(half4*)(op + d4 * 4) = r;
        }
    }
}

// ---------------------------------------------------------------------------
// Cls-token attention (4-way key split + merge)
// ---------------------------------------------------------------------------
__global__ __launch_bounds__(1024) void cls_part(
    const _Float16* __restrict__ qkvh, float* __restrict__ P)
{
    const int nh = blockIdx.x, b = blockIdx.y, sidx = blockIdx.z;
    const int j0 = sidx * 785, j1 = min(Nt, j0 + 785);
    const int tid = threadIdx.x;
    const int lane = tid & 63, wv = tid >> 6;

    const float qd = (float)qkvh[(size_t)(b * Nt) * C3 + nh * HDd + lane];
    float m = -INFINITY, l = 0.f, Od = 0.f;

    for (int j = j0 + wv; j < j1; j += 16) {
        const _Float16* base = qkvh + (size_t)(b * Nt + j) * C3 + nh * HDd;
        float prod = qd * (float)base[Cc + lane];
#pragma unroll
        for (int off = 32; off >= 1; off >>= 1)
            prod += __shfl_xor(prod, off, 64);
        float s = prod * SCALE;
        float mn = fmaxf(m, s);
        float corr = __expf(m - mn);
        float p = __expf(s - mn);
        l = l * corr + p;
        Od = fmaf(Od, corr, p * (float)base[2 * Cc + lane]);
        m = mn;
    }

    __shared__ float sm[16], sl[16], sO[16][64];
    if (lane == 0) { sm[wv] = m; sl[wv] = l; }
    sO[wv][lane] = Od;
    __syncthreads();

    if (tid < 64) {
        float M2 = sm[0];
#pragma unroll
        for (int i = 1; i < 16; ++i) M2 = fmaxf(M2, sm[i]);
        float L = 0.f, OO = 0.f;
#pragma unroll
        for (int i = 0; i < 16; ++i) {
            float f = __expf(sm[i] - M2);
            L += sl[i] * f;
            OO += sO[i][tid] * f;
        }
        float* pp = P + (size_t)((b * NHh + nh) * 4 + sidx) * 66;
        if (tid == 0) { pp[0] = M2; pp[1] = L; }
        pp[2 + tid] = OO;
    }
}

__global__ __launch_bounds__(64) void cls_merge(
    const float* __restrict__ P, _Float16* __restrict__ attH)
{
    const int nh = blockIdx.x, b = blockIdx.y;
    const int tid = threadIdx.x;
    const float* p0 = P + (size_t)(b * NHh + nh) * 4 * 66;
    float M2 = fmaxf(fmaxf(p0[0], p0[66]), fmaxf(p0[132], p0[198]));
    float L = 0.f, OO = 0.f;
#pragma unroll
    for (int i = 0; i < 4; ++i) {
        const float* pp = p0 + i * 66;
        float f = __expf(pp[0] - M2);
        L += pp[1] * f;
        OO += pp[2 + tid] * f;
    }
    attH[(size_t)(b * Nt) * Cc + nh * HDd + tid] = (_Float16)(OO / L);
}

// ---------------------------------------------------------------------------
extern "C" void kernel_launch(void* const* d_in, const int* in_sizes, int n_in,
                              void* d_out, int out_size, void* d_ws, size_t ws_size,
                              hipStream_t stream)
{
    const float* x     = (const float*)d_in[0];
    const float* Wqkv  = (const float*)d_in[1];
    const float* Wproj = (const float*)d_in[2];
    const float* bproj = (const float*)d_in[3];
    float* out = (float*)d_out;

    _Float16* qkvh;   hipGetSymbolAddress((void**)&qkvh,   HIP_SYMBOL(g_qkvh));
    float*    Ocol;   hipGetSymbolAddress((void**)&Ocol,   HIP_SYMBOL(g_Ocol));
    float*    mcol;   hipGetSymbolAddress((void**)&mcol,   HIP_SYMBOL(g_mcol));
    float*    lcol;   hipGetSymbolAddress((void**)&lcol,   HIP_SYMBOL(g_lcol));
    _Float16* xh;     hipGetSymbolAddress((void**)&xh,     HIP_SYMBOL(g_xh));
    _Float16* attH;   hipGetSymbolAddress((void**)&attH,   HIP_SYMBOL(g_attH));
    _Float16* WqkvT;  hipGetSymbolAddress((void**)&WqkvT,  HIP_SYMBOL(g_WqkvT));
    _Float16* WprojT; hipGetSymbolAddress((void**)&WprojT, HIP_SYMBOL(g_WprojT));
    float*    clsP;   hipGetSymbolAddress((void**)&clsP,   HIP_SYMBOL(g_clsP));

    // 0) prep
    cvt_f16<<<4096, 256, 0, stream>>>(x, xh, (Mrows * Cc) / 4);
    transpose_f16<<<dim3(C3 / 32, Cc / 32), 256, 0, stream>>>(Wqkv, WqkvT, Cc, C3);
    transpose_f16<<<dim3(Cc / 32, Cc / 32), 256, 0, stream>>>(Wproj, WprojT, Cc, Cc);

    // 1) qkv = x @ W_qkv  (fp16 out)
    gemm_f16<_Float16><<<dim3(C3 / 128, Mpad / 128), 256, 0, stream>>>(
        xh, WqkvT, nullptr, qkvh, Mrows, C3, Cc);

    // 2) attention
    col_attn<<<dim3(Ws, NHh, B_), 64, 0, stream>>>(qkvh, Ocol, mcol, lcol);
    cls_part<<<dim3(NHh, B_, 4), 1024, 0, stream>>>(qkvh, clsP);
    cls_merge<<<dim3(NHh, B_), 64, 0, stream>>>(clsP, attH);
    row_attn_merge<<<dim3(Hs, NHh, B_), 64, 0, stream>>>(qkvh, Ocol, mcol, lcol, attH);

    // 3) out = attH @ W_proj + b_proj  (fp32 out)
    gemm_f16<float><<<dim3(Cc / 128, Mpad / 128), 256, 0, stream>>>(
        attH, WprojT, bproj, out, Mrows, Cc, Cc);
}